// Round 1
// baseline (629.614 us; speedup 1.0000x reference)
//
#include <hip/hip_runtime.h>
#include <hip/hip_bf16.h>
#include <math.h>

// ViT encoder block, bf16-MFMA implementation.
// Geometry: B=16, N=577, C=768, H=12, Dh=64, HID=3072.
// M padded 9232 -> 9344 (73*128) so GEMM staging needs no bounds checks.

#define C_DIM   768
#define SEQ     577
#define BATCH   16
#define NHEAD   12
#define DHEAD   64
#define MREAL   (BATCH*SEQ)     /* 9232 */
#define MPAD    9344            /* 73*128 */
#define HID     3072
#define C3      (3*C_DIM)       /* 2304 */
#define NKV     640             /* padded key/query length per head */
#define CHUNK   48              /* heads per attention chunk (4 chunks of 192) */

typedef __hip_bfloat16 bf16;
typedef __attribute__((ext_vector_type(8))) short v8s;   // 8 bf16 = 4 VGPRs
typedef __attribute__((ext_vector_type(4))) float v4f;

static __device__ __forceinline__ bf16 f2b(float f){ return __float2bfloat16(f); }
static __device__ __forceinline__ float b2f(bf16 v){ return __bfloat162float(v); }

// ---------------- small kernels ----------------

__global__ __launch_bounds__(256) void k_transpose_cast(
    const float* __restrict__ src, bf16* __restrict__ dst, int R, int C)
{
  int r = blockIdx.x*256 + threadIdx.x;   // source row
  int c = blockIdx.y;                     // source col
  dst[(size_t)c*R + r] = f2b(src[(size_t)r*C + c]);
}

__global__ __launch_bounds__(256) void k_zero_pad(bf16* __restrict__ y)
{
  size_t i = (size_t)blockIdx.x*256 + threadIdx.x;
  y[(size_t)MREAL*C_DIM + i] = f2b(0.f);
}

__global__ __launch_bounds__(256) void k_layernorm(
    const float* __restrict__ in, const float* __restrict__ g,
    const float* __restrict__ b, bf16* __restrict__ o)
{
  int row = blockIdx.x, tid = threadIdx.x;
  size_t base = (size_t)row*C_DIM;
  if (row >= MREAL){
    #pragma unroll
    for (int j=0;j<3;j++) o[base + tid + j*256] = f2b(0.f);
    return;
  }
  float v[3], s=0.f, ss=0.f;
  #pragma unroll
  for (int j=0;j<3;j++){ v[j] = in[base + tid + j*256]; s += v[j]; ss += v[j]*v[j]; }
  #pragma unroll
  for (int off=32; off>0; off>>=1){ s += __shfl_xor(s,off); ss += __shfl_xor(ss,off); }
  __shared__ float red[8];
  int wv = tid>>6;
  if ((tid&63)==0){ red[wv] = s; red[4+wv] = ss; }
  __syncthreads();
  float S  = red[0]+red[1]+red[2]+red[3];
  float SS = red[4]+red[5]+red[6]+red[7];
  float mu   = S*(1.f/C_DIM);
  float rstd = rsqrtf(SS*(1.f/C_DIM) - mu*mu + 1e-5f);
  #pragma unroll
  for (int j=0;j<3;j++){
    int c = tid + j*256;
    o[base+c] = f2b((v[j]-mu)*rstd*g[c] + b[c]);
  }
}

// wave-per-row masked softmax over 640-col rows (valid cols < 577)
__global__ __launch_bounds__(64) void k_softmax(bf16* __restrict__ S)
{
  int row = blockIdx.x, z = blockIdx.y, ln = threadIdx.x;
  bf16* rp = S + ((size_t)z*NKV + row)*NKV;
  float v[10];
  float m = -1e30f;
  #pragma unroll
  for (int j=0;j<10;j++){
    int c = j*64 + ln;
    float x = (c < SEQ) ? b2f(rp[c]) : -1e30f;
    v[j] = x; m = fmaxf(m, x);
  }
  #pragma unroll
  for (int off=32; off>0; off>>=1) m = fmaxf(m, __shfl_xor(m, off));
  float sum = 0.f;
  #pragma unroll
  for (int j=0;j<10;j++){
    int c = j*64 + ln;
    float e = (c < SEQ) ? expf(v[j]-m) : 0.f;
    v[j] = e; sum += e;
  }
  #pragma unroll
  for (int off=32; off>0; off>>=1) sum += __shfl_xor(sum, off);
  float inv = 1.f/sum;
  #pragma unroll
  for (int j=0;j<10;j++){
    int c = j*64 + ln;
    rp[c] = f2b(v[j]*inv);
  }
}

// Vt[z][d][key] = V[b,h,key,d]  (so PV GEMM sees B^T with contiguous K)
__global__ __launch_bounds__(64) void k_vt(
    const bf16* __restrict__ qkv, bf16* __restrict__ Vt, int chunk0)
{
  int key = blockIdx.x, z = blockIdx.y, d = threadIdx.x;
  int hh = chunk0 + z, b = hh/NHEAD, h = hh%NHEAD;
  Vt[((size_t)z*DHEAD + d)*NKV + key] =
      qkv[(size_t)(b*SEQ + key)*C3 + 2*C_DIM + h*DHEAD + d];
}

// ---------------- MFMA GEMM: C[M,N] = A[M,K] * BT[N,K]^T ----------------
// 128x128 tile, BK=64, 4 waves (2x2), each wave 4x4 16x16x32 fragments.
// EPI 0: qkv   -> bf16, +bias, *0.125 for cols<768 (fold attn scale into q)
// EPI 1: fc1   -> bf16, +bias, exact GELU
// EPI 2: resid -> fp32, +bias +resid[idx], guarded row<MREAL
// EPI 3: scores-> bf16 into S[z][row][col], per-head A/B bases from qkv
// EPI 4: pv    -> bf16 into y[(b*577+row)*768 + h*64+col], guards row<577,col<64
template<int EPI>
__global__ __launch_bounds__(256, 2) void gemm_bt(
    const bf16* __restrict__ A, int lda,
    const bf16* __restrict__ BT, int ldb,
    void* Cv, int ldc,
    const float* __restrict__ bias,
    const float* resid,
    int K, int chunk0)
{
  __shared__ alignas(16) bf16 sA[128*64];
  __shared__ alignas(16) bf16 sB[128*64];
  const int tid  = threadIdx.x;
  const int wave = tid>>6, lane = tid&63;
  const int wr = wave>>1, wc = wave&1;
  const int r16 = lane&15, kg = lane>>4;
  const int mt = blockIdx.y, nt = blockIdx.x, z = blockIdx.z;

  const bf16* Ap = A;
  const bf16* Bp = BT;
  int b_ = 0, h_ = 0;
  if constexpr (EPI==3){
    int hh = chunk0 + z; b_ = hh/NHEAD; h_ = hh%NHEAD;
    Ap = A  + (size_t)(b_*SEQ)*lda + h_*DHEAD;            // q block
    Bp = BT + (size_t)(b_*SEQ)*ldb + C_DIM + h_*DHEAD;    // k block
  }
  if constexpr (EPI==4){
    int hh = chunk0 + z; b_ = hh/NHEAD; h_ = hh%NHEAD;
    Ap = A  + (size_t)z*NKV*NKV;    // P for this head
    Bp = BT + (size_t)z*DHEAD*NKV;  // Vt for this head
  }

  v4f acc[4][4];
  v4f zero4 = {0.f,0.f,0.f,0.f};
  #pragma unroll
  for (int m=0;m<4;m++)
    #pragma unroll
    for (int n=0;n<4;n++) acc[m][n] = zero4;

  const int mrow0 = mt*128, ncol0 = nt*128;

  for (int kt=0; kt<K; kt+=64){
    // stage A,B tiles (128x64 bf16 each) via async global->LDS, 16B/lane
    #pragma unroll
    for (int i=0;i<4;i++){
      int ci = wave*4 + i;          // 16 one-KiB segments per tile
      int q  = ci*64 + lane;        // 16B chunk index
      int rr = q>>3;                // tile row
      int cc = (q&7)*8;             // tile col (elements)
      const bf16* ga = Ap + (size_t)(mrow0+rr)*lda + (kt+cc);
      const bf16* gb = Bp + (size_t)(ncol0+rr)*ldb + (kt+cc);
      __builtin_amdgcn_global_load_lds(
          (const __attribute__((address_space(1))) void*)ga,
          (__attribute__((address_space(3))) void*)((char*)sA + ci*1024), 16, 0, 0);
      __builtin_amdgcn_global_load_lds(
          (const __attribute__((address_space(1))) void*)gb,
          (__attribute__((address_space(3))) void*)((char*)sB + ci*1024), 16, 0, 0);
    }
    __syncthreads();
    #pragma unroll
    for (int ks=0; ks<2; ks++){
      v8s av[4], bv[4];
      #pragma unroll
      for (int m=0;m<4;m++)
        av[m] = *(const v8s*)(sA + (wr*64 + m*16 + r16)*64 + ks*32 + kg*8);
      #pragma unroll
      for (int n=0;n<4;n++)
        bv[n] = *(const v8s*)(sB + (wc*64 + n*16 + r16)*64 + ks*32 + kg*8);
      #pragma unroll
      for (int m=0;m<4;m++)
        #pragma unroll
        for (int n=0;n<4;n++)
          acc[m][n] = __builtin_amdgcn_mfma_f32_16x16x32_bf16(av[m], bv[n], acc[m][n], 0, 0, 0);
    }
    __syncthreads();
  }

  // epilogue — verified C/D layout: col = lane&15, row = (lane>>4)*4 + reg
  #pragma unroll
  for (int m=0;m<4;m++){
    #pragma unroll
    for (int n=0;n<4;n++){
      int col = ncol0 + wc*64 + n*16 + r16;
      #pragma unroll
      for (int gg=0; gg<4; gg++){
        int row = mrow0 + wr*64 + m*16 + kg*4 + gg;
        float v = acc[m][n][gg];
        if constexpr (EPI==0){
          float o = v + bias[col];
          if (col < C_DIM) o *= 0.125f;   // Dh^-0.5 folded into q
          ((bf16*)Cv)[(size_t)row*ldc + col] = f2b(o);
        } else if constexpr (EPI==1){
          float xg = v + bias[col];
          float o = 0.5f*xg*(1.f + erff(xg*0.70710678118654752f));
          ((bf16*)Cv)[(size_t)row*ldc + col] = f2b(o);
        } else if constexpr (EPI==2){
          if (row < MREAL){
            size_t idx = (size_t)row*ldc + col;
            ((float*)Cv)[idx] = v + bias[col] + resid[idx];
          }
        } else if constexpr (EPI==3){
          ((bf16*)Cv)[((size_t)z*NKV + row)*NKV + col] = f2b(v);
        } else { // EPI==4
          if (row < SEQ && col < DHEAD){
            ((bf16*)Cv)[(size_t)(b_*SEQ + row)*C_DIM + h_*DHEAD + col] = f2b(v);
          }
        }
      }
    }
  }
}

// ---------------- launch ----------------

extern "C" void kernel_launch(void* const* d_in, const int* in_sizes, int n_in,
                              void* d_out, int out_size, void* d_ws, size_t ws_size,
                              hipStream_t stream)
{
  const float* x     = (const float*)d_in[0];
  const float* ln1g  = (const float*)d_in[1];
  const float* ln1b  = (const float*)d_in[2];
  const float* qkvw  = (const float*)d_in[3];
  const float* qkvb  = (const float*)d_in[4];
  const float* projw = (const float*)d_in[5];
  const float* projb = (const float*)d_in[6];
  const float* ln2g  = (const float*)d_in[7];
  const float* ln2b  = (const float*)d_in[8];
  const float* fc1w  = (const float*)d_in[9];
  const float* fc1b  = (const float*)d_in[10];
  const float* fc2w  = (const float*)d_in[11];
  const float* fc2b  = (const float*)d_in[12];
  float* out = (float*)d_out;

  char* p = (char*)d_ws;
  auto take = [&](size_t n){ char* r = p; p += (n + 255) & ~(size_t)255; return r; };
  bf16* qkvT = (bf16*)take((size_t)C3*C_DIM*2);        // [2304][768]
  bf16* projT= (bf16*)take((size_t)C_DIM*C_DIM*2);     // [768][768]
  bf16* fc1T = (bf16*)take((size_t)HID*C_DIM*2);       // [3072][768]
  bf16* fc2T = (bf16*)take((size_t)C_DIM*HID*2);       // [768][3072]
  bf16* xn   = (bf16*)take((size_t)MPAD*C_DIM*2);
  bf16* xn2  = (bf16*)take((size_t)MPAD*C_DIM*2);
  bf16* qkv  = (bf16*)take((size_t)MPAD*C3*2);
  bf16* y    = (bf16*)take((size_t)MPAD*C_DIM*2);
  bf16* h    = (bf16*)take((size_t)MPAD*HID*2);
  bf16* Sb   = (bf16*)take((size_t)CHUNK*NKV*NKV*2);
  bf16* Vt   = (bf16*)take((size_t)(CHUNK+1)*DHEAD*NKV*2); // +1 head pad for col-overread
  // total ~202 MB

  // weight transposes (bf16 cast), every call (stateless)
  k_transpose_cast<<<dim3(3, C3),  256, 0, stream>>>(qkvw, qkvT, C_DIM, C3);
  k_transpose_cast<<<dim3(3, C_DIM),256, 0, stream>>>(projw, projT, C_DIM, C_DIM);
  k_transpose_cast<<<dim3(3, HID), 256, 0, stream>>>(fc1w, fc1T, C_DIM, HID);
  k_transpose_cast<<<dim3(12,C_DIM),256, 0, stream>>>(fc2w, fc2T, HID, C_DIM);
  k_zero_pad<<<336, 256, 0, stream>>>(y);

  // LN1 -> xn
  k_layernorm<<<MPAD, 256, 0, stream>>>(x, ln1g, ln1b, xn);

  // qkv = xn @ qkv_w + b   (q scaled by 0.125)
  gemm_bt<0><<<dim3(C3/128, MPAD/128), 256, 0, stream>>>(
      xn, C_DIM, qkvT, C_DIM, qkv, C3, qkvb, nullptr, C_DIM, 0);

  // attention, 48 heads per chunk
  for (int c0 = 0; c0 < BATCH*NHEAD; c0 += CHUNK){
    gemm_bt<3><<<dim3(NKV/128, NKV/128, CHUNK), 256, 0, stream>>>(
        qkv, C3, qkv, C3, Sb, NKV, nullptr, nullptr, DHEAD, c0);
    k_softmax<<<dim3(NKV, CHUNK), 64, 0, stream>>>(Sb);
    k_vt<<<dim3(NKV, CHUNK), 64, 0, stream>>>(qkv, Vt, c0);
    gemm_bt<4><<<dim3(1, NKV/128, CHUNK), 256, 0, stream>>>(
        Sb, NKV, Vt, NKV, y, C_DIM, nullptr, nullptr, NKV, c0);
  }

  // x1 = x + y @ proj_w + b   -> d_out (fp32)
  gemm_bt<2><<<dim3(C_DIM/128, MPAD/128), 256, 0, stream>>>(
      y, C_DIM, projT, C_DIM, out, C_DIM, projb, x, C_DIM, 0);

  // LN2 -> xn2
  k_layernorm<<<MPAD, 256, 0, stream>>>(out, ln2g, ln2b, xn2);

  // h = gelu(xn2 @ fc1_w + b)
  gemm_bt<1><<<dim3(HID/128, MPAD/128), 256, 0, stream>>>(
      xn2, C_DIM, fc1T, C_DIM, h, HID, fc1b, nullptr, C_DIM, 0);

  // out = x1 + h @ fc2_w + b
  gemm_bt<2><<<dim3(C_DIM/128, MPAD/128), 256, 0, stream>>>(
      h, HID, fc2T, HID, out, C_DIM, fc2b, out, HID, 0);
}

// Round 2
// 508.253 us; speedup vs baseline: 1.2388x; 1.2388x over previous
//
#include <hip/hip_runtime.h>
#include <hip/hip_bf16.h>
#include <math.h>

// ViT encoder block, bf16-MFMA implementation. Round 2:
//  - XCD-bijective block swizzle (m204) on all z==1 GEMMs
//  - __launch_bounds__(256,4)
//  - V computed as transposed GEMM (Wv^T @ xn^T) with coalesced epilogue (EPI 5);
//    qkv GEMM shrinks to q,k only (1536 cols); k_vt eliminated
//  - softmax: exp2f with log2e folded into q-scale, ushort2 vector I/O
//  - LDS-tiled coalesced weight transpose

#define C_DIM   768
#define SEQ     577
#define BATCH   16
#define NHEAD   12
#define DHEAD   64
#define MREAL   (BATCH*SEQ)     /* 9232 */
#define MPAD    9344            /* 73*128 */
#define HID     3072
#define QKW     1536            /* q,k concatenated width */
#define NKV     640             /* padded key/query length per head */
#define CHUNK   48              /* heads per attention chunk */
#define QSCALE  0.1803368801111204f  /* Dh^-0.5 * log2(e), for exp2 softmax */

typedef __hip_bfloat16 bf16;
typedef __attribute__((ext_vector_type(8))) short v8s;   // 8 bf16 = 4 VGPRs
typedef __attribute__((ext_vector_type(4))) float v4f;

static __device__ __forceinline__ bf16 f2b(float f){ return __float2bfloat16(f); }
static __device__ __forceinline__ float us2f(unsigned short u){
  union{ float f; unsigned int i; } x; x.i = ((unsigned int)u)<<16; return x.f;
}
static __device__ __forceinline__ unsigned short f2us(float f){
  bf16 t = __float2bfloat16(f); return *(unsigned short*)&t;
}

// ---------------- small kernels ----------------

// 64x64 LDS-tiled transpose + fp32->bf16 cast: dst[c][r] = src[r][c]
__global__ __launch_bounds__(256) void k_transpose_cast(
    const float* __restrict__ src, bf16* __restrict__ dst, int R, int C)
{
  __shared__ float s[64][65];
  const int tr = blockIdx.x*64, tc = blockIdx.y*64;
  const int t = threadIdx.x;
  const int lr = t >> 4, lc4 = t & 15;
  #pragma unroll
  for (int i=0;i<4;i++){
    int r = lr + i*16;
    float4 v = *(const float4*)(src + (size_t)(tr+r)*C + tc + lc4*4);
    s[r][lc4*4+0]=v.x; s[r][lc4*4+1]=v.y; s[r][lc4*4+2]=v.z; s[r][lc4*4+3]=v.w;
  }
  __syncthreads();
  const int c = t >> 2, seg = t & 3;
  alignas(16) bf16 tmp[16];
  #pragma unroll
  for (int j=0;j<16;j++) tmp[j] = f2b(s[seg*16+j][c]);
  bf16* dp = dst + (size_t)(tc+c)*R + tr + seg*16;
  *(uint4*)dp       = *(uint4*)tmp;
  *(uint4*)(dp + 8) = *(uint4*)(tmp + 8);
}

__global__ __launch_bounds__(256) void k_zero_pad(bf16* __restrict__ y)
{
  size_t i = (size_t)blockIdx.x*256 + threadIdx.x;
  y[(size_t)MREAL*C_DIM + i] = f2b(0.f);
}

__global__ __launch_bounds__(256) void k_layernorm(
    const float* __restrict__ in, const float* __restrict__ g,
    const float* __restrict__ b, bf16* __restrict__ o)
{
  int row = blockIdx.x, tid = threadIdx.x;
  size_t base = (size_t)row*C_DIM;
  if (row >= MREAL){
    #pragma unroll
    for (int j=0;j<3;j++) o[base + tid + j*256] = f2b(0.f);
    return;
  }
  float v[3], s=0.f, ss=0.f;
  #pragma unroll
  for (int j=0;j<3;j++){ v[j] = in[base + tid + j*256]; s += v[j]; ss += v[j]*v[j]; }
  #pragma unroll
  for (int off=32; off>0; off>>=1){ s += __shfl_xor(s,off); ss += __shfl_xor(ss,off); }
  __shared__ float red[8];
  int wv = tid>>6;
  if ((tid&63)==0){ red[wv] = s; red[4+wv] = ss; }
  __syncthreads();
  float S  = red[0]+red[1]+red[2]+red[3];
  float SS = red[4]+red[5]+red[6]+red[7];
  float mu   = S*(1.f/C_DIM);
  float rstd = rsqrtf(SS*(1.f/C_DIM) - mu*mu + 1e-5f);
  #pragma unroll
  for (int j=0;j<3;j++){
    int c = tid + j*256;
    o[base+c] = f2b((v[j]-mu)*rstd*g[c] + b[c]);
  }
}

// wave-per-row masked softmax over 640-col rows; scores are in log2 units
__global__ __launch_bounds__(64) void k_softmax(bf16* __restrict__ S)
{
  int row = blockIdx.x, z = blockIdx.y, ln = threadIdx.x;
  bf16* rp = S + ((size_t)z*NKV + row)*NKV;
  float v[10];
  float m = -1e30f;
  #pragma unroll
  for (int j=0;j<5;j++){
    int c = j*128 + ln*2;
    ushort2 u = *(const ushort2*)(rp + c);
    float a = (c   < SEQ) ? us2f(u.x) : -1e30f;
    float b = (c+1 < SEQ) ? us2f(u.y) : -1e30f;
    v[2*j] = a; v[2*j+1] = b;
    m = fmaxf(m, fmaxf(a, b));
  }
  #pragma unroll
  for (int off=32; off>0; off>>=1) m = fmaxf(m, __shfl_xor(m, off));
  float sum = 0.f;
  #pragma unroll
  for (int j=0;j<10;j++){
    float e = exp2f(v[j]-m);   // masked lanes: exp2(-inf-ish) = 0
    v[j] = e; sum += e;
  }
  #pragma unroll
  for (int off=32; off>0; off>>=1) sum += __shfl_xor(sum, off);
  float inv = 1.f/sum;
  #pragma unroll
  for (int j=0;j<5;j++){
    int c = j*128 + ln*2;
    ushort2 o2; o2.x = f2us(v[2*j]*inv); o2.y = f2us(v[2*j+1]*inv);
    *(ushort2*)(rp + c) = o2;
  }
}

// ---------------- MFMA GEMM: C[M,N] = A[M,K] * BT[N,K]^T ----------------
// 128x128 tile, BK=64, 4 waves (2x2), each wave 4x4 16x16x32 fragments.
// EPI 0: qk    -> bf16, +bias, *QSCALE for cols<768 (scale+log2e folded into q)
// EPI 1: fc1   -> bf16, +bias, exact GELU
// EPI 2: resid -> fp32, +bias +resid[idx], guarded row<MREAL
// EPI 3: scores-> bf16 into S[z][row][col], per-head A/B bases from qk buffer
// EPI 4: pv    -> bf16 into y[(b*577+row)*768 + h*64+col], guards row<577,col<64
// EPI 5: vT    -> bf16 into VtAll[b*768+row][key], row=v-outdim, col=token, +bias[row]
template<int EPI>
__global__ __launch_bounds__(256, 4) void gemm_bt(
    const bf16* __restrict__ A, int lda,
    const bf16* __restrict__ BT, int ldb,
    void* Cv, int ldc,
    const float* __restrict__ bias,
    const float* resid,
    int K, int chunk0)
{
  __shared__ alignas(16) bf16 sA[128*64];
  __shared__ alignas(16) bf16 sB[128*64];
  const int tid  = threadIdx.x;
  const int wave = tid>>6, lane = tid&63;
  const int wr = wave>>1, wc = wave&1;
  const int r16 = lane&15, kg = lane>>4;

  int mt, nt;
  const int z = blockIdx.z;
  if constexpr (EPI==3 || EPI==4){
    mt = blockIdx.y; nt = blockIdx.x;
  } else {
    // XCD-bijective swizzle (m204): contiguous tile chunk per XCD
    int nx = gridDim.x, nwg = nx*gridDim.y;
    int id = blockIdx.y*nx + blockIdx.x;
    int qq = nwg>>3, r8 = nwg&7, xcd = id&7, j = id>>3;
    int swz = (xcd<r8 ? xcd*(qq+1) : r8*(qq+1) + (xcd-r8)*qq) + j;
    mt = swz / nx; nt = swz % nx;
  }

  const bf16* Ap = A;
  const bf16* Bp = BT;
  int b_ = 0, h_ = 0;
  if constexpr (EPI==3){
    int hh = chunk0 + z; b_ = hh/NHEAD; h_ = hh%NHEAD;
    Ap = A  + (size_t)(b_*SEQ)*lda + h_*DHEAD;                 // q block
    Bp = BT + (size_t)(b_*SEQ)*ldb + C_DIM + h_*DHEAD;         // k block
  }
  if constexpr (EPI==4){
    int hh = chunk0 + z; b_ = hh/NHEAD; h_ = hh%NHEAD;
    Ap = A  + (size_t)z*NKV*NKV;            // P for this head (chunk-local)
    Bp = BT + (size_t)hh*DHEAD*NKV;         // VtAll rows for this head
  }

  v4f acc[4][4];
  v4f zero4 = {0.f,0.f,0.f,0.f};
  #pragma unroll
  for (int m=0;m<4;m++)
    #pragma unroll
    for (int n=0;n<4;n++) acc[m][n] = zero4;

  const int mrow0 = mt*128, ncol0 = nt*128;

  for (int kt=0; kt<K; kt+=64){
    #pragma unroll
    for (int i=0;i<4;i++){
      int ci = wave*4 + i;
      int q  = ci*64 + lane;
      int rr = q>>3;
      int cc = (q&7)*8;
      const bf16* ga = Ap + (size_t)(mrow0+rr)*lda + (kt+cc);
      const bf16* gb = Bp + (size_t)(ncol0+rr)*ldb + (kt+cc);
      __builtin_amdgcn_global_load_lds(
          (const __attribute__((address_space(1))) void*)ga,
          (__attribute__((address_space(3))) void*)((char*)sA + ci*1024), 16, 0, 0);
      __builtin_amdgcn_global_load_lds(
          (const __attribute__((address_space(1))) void*)gb,
          (__attribute__((address_space(3))) void*)((char*)sB + ci*1024), 16, 0, 0);
    }
    __syncthreads();
    #pragma unroll
    for (int ks=0; ks<2; ks++){
      v8s av[4], bv[4];
      #pragma unroll
      for (int m=0;m<4;m++)
        av[m] = *(const v8s*)(sA + (wr*64 + m*16 + r16)*64 + ks*32 + kg*8);
      #pragma unroll
      for (int n=0;n<4;n++)
        bv[n] = *(const v8s*)(sB + (wc*64 + n*16 + r16)*64 + ks*32 + kg*8);
      #pragma unroll
      for (int m=0;m<4;m++)
        #pragma unroll
        for (int n=0;n<4;n++)
          acc[m][n] = __builtin_amdgcn_mfma_f32_16x16x32_bf16(av[m], bv[n], acc[m][n], 0, 0, 0);
    }
    __syncthreads();
  }

  // epilogue — C/D layout: col = lane&15, row = (lane>>4)*4 + reg
  #pragma unroll
  for (int m=0;m<4;m++){
    #pragma unroll
    for (int n=0;n<4;n++){
      int col = ncol0 + wc*64 + n*16 + r16;
      #pragma unroll
      for (int gg=0; gg<4; gg++){
        int row = mrow0 + wr*64 + m*16 + kg*4 + gg;
        float v = acc[m][n][gg];
        if constexpr (EPI==0){
          float o = v + bias[col];
          if (col < C_DIM) o *= QSCALE;
          ((bf16*)Cv)[(size_t)row*ldc + col] = f2b(o);
        } else if constexpr (EPI==1){
          float xg = v + bias[col];
          float o = 0.5f*xg*(1.f + erff(xg*0.70710678118654752f));
          ((bf16*)Cv)[(size_t)row*ldc + col] = f2b(o);
        } else if constexpr (EPI==2){
          if (row < MREAL){
            size_t idx = (size_t)row*ldc + col;
            ((float*)Cv)[idx] = v + bias[col] + resid[idx];
          }
        } else if constexpr (EPI==3){
          ((bf16*)Cv)[((size_t)z*NKV + row)*NKV + col] = f2b(v);
        } else if constexpr (EPI==4){
          if (row < SEQ && col < DHEAD){
            ((bf16*)Cv)[(size_t)(b_*SEQ + row)*C_DIM + h_*DHEAD + col] = f2b(v);
          }
        } else { // EPI==5: row = v-outdim (h*64+d), col = global token g
          int g = col;
          if (g < MREAL){
            int b = g / SEQ;
            int key = g - b*SEQ;
            ((bf16*)Cv)[((size_t)b*C_DIM + row)*NKV + key] = f2b(v + bias[row]);
          }
        }
      }
    }
  }
}

// ---------------- launch ----------------

extern "C" void kernel_launch(void* const* d_in, const int* in_sizes, int n_in,
                              void* d_out, int out_size, void* d_ws, size_t ws_size,
                              hipStream_t stream)
{
  const float* x     = (const float*)d_in[0];
  const float* ln1g  = (const float*)d_in[1];
  const float* ln1b  = (const float*)d_in[2];
  const float* qkvw  = (const float*)d_in[3];
  const float* qkvb  = (const float*)d_in[4];
  const float* projw = (const float*)d_in[5];
  const float* projb = (const float*)d_in[6];
  const float* ln2g  = (const float*)d_in[7];
  const float* ln2b  = (const float*)d_in[8];
  const float* fc1w  = (const float*)d_in[9];
  const float* fc1b  = (const float*)d_in[10];
  const float* fc2w  = (const float*)d_in[11];
  const float* fc2b  = (const float*)d_in[12];
  float* out = (float*)d_out;

  char* p = (char*)d_ws;
  auto take = [&](size_t n){ char* r = p; p += (n + 255) & ~(size_t)255; return r; };
  bf16* qkvT = (bf16*)take((size_t)(3*C_DIM)*C_DIM*2);  // [2304][768] (q,k,v rows)
  bf16* projT= (bf16*)take((size_t)C_DIM*C_DIM*2);
  bf16* fc1T = (bf16*)take((size_t)HID*C_DIM*2);
  bf16* fc2T = (bf16*)take((size_t)C_DIM*HID*2);
  bf16* xn   = (bf16*)take((size_t)MPAD*C_DIM*2);
  bf16* xn2  = (bf16*)take((size_t)MPAD*C_DIM*2);
  bf16* qk   = (bf16*)take((size_t)MPAD*QKW*2);          // q,k only
  bf16* y    = (bf16*)take((size_t)MPAD*C_DIM*2);
  bf16* h    = (bf16*)take((size_t)MPAD*HID*2);
  bf16* Sb   = (bf16*)take((size_t)CHUNK*NKV*NKV*2);
  bf16* VtAll= (bf16*)take((size_t)(BATCH*C_DIM + 2*DHEAD)*NKV*2); // [b*768+vo][key], +pad rows
  // total ~198 MB

  // weight transposes (bf16 cast)
  k_transpose_cast<<<dim3(C_DIM/64, 3*C_DIM/64), 256, 0, stream>>>(qkvw, qkvT, C_DIM, 3*C_DIM);
  k_transpose_cast<<<dim3(C_DIM/64, C_DIM/64),  256, 0, stream>>>(projw, projT, C_DIM, C_DIM);
  k_transpose_cast<<<dim3(C_DIM/64, HID/64),    256, 0, stream>>>(fc1w, fc1T, C_DIM, HID);
  k_transpose_cast<<<dim3(HID/64,  C_DIM/64),   256, 0, stream>>>(fc2w, fc2T, HID, C_DIM);
  k_zero_pad<<<336, 256, 0, stream>>>(y);

  // LN1 -> xn
  k_layernorm<<<MPAD, 256, 0, stream>>>(x, ln1g, ln1b, xn);

  // qk = xn @ [Wq|Wk]^T + b  (q scaled by QSCALE)
  gemm_bt<0><<<dim3(QKW/128, MPAD/128), 256, 0, stream>>>(
      xn, C_DIM, qkvT, C_DIM, qk, QKW, qkvb, nullptr, C_DIM, 0);

  // VtAll = (xn @ Wv)^T + bv, written as [b*768+vo][key]
  gemm_bt<5><<<dim3(MPAD/128, C_DIM/128), 256, 0, stream>>>(
      qkvT + (size_t)QKW*C_DIM, C_DIM, xn, C_DIM, VtAll, 0,
      qkvb + 2*C_DIM, nullptr, C_DIM, 0);

  // attention, CHUNK heads at a time
  for (int c0 = 0; c0 < BATCH*NHEAD; c0 += CHUNK){
    gemm_bt<3><<<dim3(NKV/128, NKV/128, CHUNK), 256, 0, stream>>>(
        qk, QKW, qk, QKW, Sb, NKV, nullptr, nullptr, DHEAD, c0);
    k_softmax<<<dim3(NKV, CHUNK), 64, 0, stream>>>(Sb);
    gemm_bt<4><<<dim3(1, NKV/128, CHUNK), 256, 0, stream>>>(
        Sb, NKV, VtAll, NKV, y, C_DIM, nullptr, nullptr, NKV, c0);
  }

  // x1 = x + y @ proj_w + b   -> d_out (fp32)
  gemm_bt<2><<<dim3(C_DIM/128, MPAD/128), 256, 0, stream>>>(
      y, C_DIM, projT, C_DIM, out, C_DIM, projb, x, C_DIM, 0);

  // LN2 -> xn2
  k_layernorm<<<MPAD, 256, 0, stream>>>(out, ln2g, ln2b, xn2);

  // h = gelu(xn2 @ fc1_w + b)
  gemm_bt<1><<<dim3(HID/128, MPAD/128), 256, 0, stream>>>(
      xn2, C_DIM, fc1T, C_DIM, h, HID, fc1b, nullptr, C_DIM, 0);

  // out = x1 + h @ fc2_w + b
  gemm_bt<2><<<dim3(C_DIM/128, MPAD/128), 256, 0, stream>>>(
      h, HID, fc2T, HID, out, C_DIM, fc2b, out, HID, 0);
}

// Round 3
// 340.803 us; speedup vs baseline: 1.8474x; 1.4913x over previous
//
#include <hip/hip_runtime.h>
#include <hip/hip_bf16.h>
#include <math.h>

// ViT encoder block, bf16-MFMA. Round 3: fused flash attention.
//  - k_flash: per block = 1 head x 64 q-rows; S^T = mfma(K, Q^T) so lane owns
//    one q-column; online softmax with shfl_xor(16/32); P^T via per-wave LDS;
//    PV as o^T = mfma(V^T, P^T). K/V double-buffered via global_load_lds with
//    XOR-swizzled source + swizzled reads. Replaces scores/softmax/PV chain.
//  - everything else unchanged from round 2.

#define C_DIM   768
#define SEQ     577
#define BATCH   16
#define NHEAD   12
#define DHEAD   64
#define MREAL   (BATCH*SEQ)     /* 9232 */
#define MPAD    9344            /* 73*128 */
#define HID     3072
#define QKW     1536            /* q,k concatenated width */
#define NKV     640             /* padded key length per head (VtAll cols) */
#define QSCALE  0.1803368801111204f  /* Dh^-0.5 * log2(e), for exp2 softmax */

typedef __hip_bfloat16 bf16;
typedef __attribute__((ext_vector_type(8))) short v8s;   // 8 bf16 = 4 VGPRs
typedef __attribute__((ext_vector_type(4))) float v4f;

static __device__ __forceinline__ bf16 f2b(float f){ return __float2bfloat16(f); }
static __device__ __forceinline__ float us2f(unsigned short u){
  union{ float f; unsigned int i; } x; x.i = ((unsigned int)u)<<16; return x.f;
}
static __device__ __forceinline__ short f2s(float f){
  bf16 t = __float2bfloat16(f); return *(short*)&t;
}

// ---------------- small kernels ----------------

// 64x64 LDS-tiled transpose + fp32->bf16 cast: dst[c][r] = src[r][c]
__global__ __launch_bounds__(256) void k_transpose_cast(
    const float* __restrict__ src, bf16* __restrict__ dst, int R, int C)
{
  __shared__ float s[64][65];
  const int tr = blockIdx.x*64, tc = blockIdx.y*64;
  const int t = threadIdx.x;
  const int lr = t >> 4, lc4 = t & 15;
  #pragma unroll
  for (int i=0;i<4;i++){
    int r = lr + i*16;
    float4 v = *(const float4*)(src + (size_t)(tr+r)*C + tc + lc4*4);
    s[r][lc4*4+0]=v.x; s[r][lc4*4+1]=v.y; s[r][lc4*4+2]=v.z; s[r][lc4*4+3]=v.w;
  }
  __syncthreads();
  const int c = t >> 2, seg = t & 3;
  alignas(16) bf16 tmp[16];
  #pragma unroll
  for (int j=0;j<16;j++) tmp[j] = f2b(s[seg*16+j][c]);
  bf16* dp = dst + (size_t)(tc+c)*R + tr + seg*16;
  *(uint4*)dp       = *(uint4*)tmp;
  *(uint4*)(dp + 8) = *(uint4*)(tmp + 8);
}

__global__ __launch_bounds__(256) void k_zero_pad(bf16* __restrict__ y)
{
  size_t i = (size_t)blockIdx.x*256 + threadIdx.x;
  y[(size_t)MREAL*C_DIM + i] = f2b(0.f);
}

__global__ __launch_bounds__(256) void k_layernorm(
    const float* __restrict__ in, const float* __restrict__ g,
    const float* __restrict__ b, bf16* __restrict__ o)
{
  int row = blockIdx.x, tid = threadIdx.x;
  size_t base = (size_t)row*C_DIM;
  if (row >= MREAL){
    #pragma unroll
    for (int j=0;j<3;j++) o[base + tid + j*256] = f2b(0.f);
    return;
  }
  float v[3], s=0.f, ss=0.f;
  #pragma unroll
  for (int j=0;j<3;j++){ v[j] = in[base + tid + j*256]; s += v[j]; ss += v[j]*v[j]; }
  #pragma unroll
  for (int off=32; off>0; off>>=1){ s += __shfl_xor(s,off); ss += __shfl_xor(ss,off); }
  __shared__ float red[8];
  int wv = tid>>6;
  if ((tid&63)==0){ red[wv] = s; red[4+wv] = ss; }
  __syncthreads();
  float S  = red[0]+red[1]+red[2]+red[3];
  float SS = red[4]+red[5]+red[6]+red[7];
  float mu   = S*(1.f/C_DIM);
  float rstd = rsqrtf(SS*(1.f/C_DIM) - mu*mu + 1e-5f);
  #pragma unroll
  for (int j=0;j<3;j++){
    int c = tid + j*256;
    o[base+c] = f2b((v[j]-mu)*rstd*g[c] + b[c]);
  }
}

// ---------------- fused flash attention ----------------
// Grid: 1920 blocks (192 heads x 10 q-tiles of 64), 256 threads (4 waves x 16 q).
// Per kv-tile (64 keys): S^T = mfma(A=K, B=Q^T)  -> lane q-col = lane&15
//   online softmax (in-lane + shfl_xor 16/32), P^T -> per-wave LDS ->
//   o^T[d][q] += mfma(A=V^T, B=P^T).
__global__ __launch_bounds__(256, 3) void k_flash(
    const bf16* __restrict__ qk, const bf16* __restrict__ VtAll,
    bf16* __restrict__ y)
{
  __shared__ alignas(16) bf16 sK[2][64*64];
  __shared__ alignas(16) bf16 sV[2][64*64];
  __shared__ alignas(16) bf16 sP[4][16*72];

  const int tid = threadIdx.x;
  const int wave = tid>>6, lane = tid&63;
  const int r16 = lane&15, kg = lane>>4;

  // XCD swizzle: 1920 = 8 * 240; each XCD gets 24 whole heads
  const int id = blockIdx.x;
  const int swz = (id&7)*240 + (id>>3);
  const int hh = swz/10, qt = swz - hh*10;
  const int b_ = hh/NHEAD, h_ = hh - b_*NHEAD;

  // Q fragments (B-operand): lane q = r16, d = ks*32 + kg*8 + j
  const int qrow = b_*SEQ + qt*64 + wave*16 + r16;   // in-bounds of qk buffer
  v8s qf[2];
  qf[0] = *(const v8s*)(qk + (size_t)qrow*QKW + h_*DHEAD + kg*8);
  qf[1] = *(const v8s*)(qk + (size_t)qrow*QKW + h_*DHEAD + 32 + kg*8);

  auto stage = [&](int kt, int buf){
    #pragma unroll
    for (int i=0;i<2;i++){
      int chunk = i*256 + tid;
      int row = chunk>>3, ch = chunk&7;
      int sc = ch ^ (row&7);                      // pre-swizzled source column
      const bf16* gk = qk + (size_t)(b_*SEQ + kt*64 + row)*QKW
                          + C_DIM + h_*DHEAD + sc*8;
      const bf16* gv = VtAll + (size_t)(b_*C_DIM + h_*DHEAD + row)*NKV
                             + kt*64 + sc*8;
      __builtin_amdgcn_global_load_lds(
          (const __attribute__((address_space(1))) void*)gk,
          (__attribute__((address_space(3))) void*)((char*)&sK[buf][0] + i*4096 + wave*1024),
          16, 0, 0);
      __builtin_amdgcn_global_load_lds(
          (const __attribute__((address_space(1))) void*)gv,
          (__attribute__((address_space(3))) void*)((char*)&sV[buf][0] + i*4096 + wave*1024),
          16, 0, 0);
    }
  };

  float m_run = -1e30f, l_run = 0.f;
  v4f zero4 = {0.f,0.f,0.f,0.f};
  v4f o[4] = {zero4, zero4, zero4, zero4};

  stage(0, 0);
  for (int kt=0; kt<10; ++kt){
    __syncthreads();                 // drains vmcnt: stage(kt) complete; all waves done with kt-1
    if (kt < 9) stage(kt+1, (kt+1)&1);
    const bf16* Kt = &sK[kt&1][0];
    const bf16* Vt = &sV[kt&1][0];

    // S^T fragments: sfr[m] covers keys m*16 + (kg*4 + gg), q = r16
    v4f sfr[4] = {zero4, zero4, zero4, zero4};
    #pragma unroll
    for (int ks=0; ks<2; ++ks){
      #pragma unroll
      for (int m=0;m<4;m++){
        int key = m*16 + r16;
        v8s kf = *(const v8s*)(Kt + key*64 + (((ks*4+kg) ^ (key&7))*8));
        sfr[m] = __builtin_amdgcn_mfma_f32_16x16x32_bf16(kf, qf[ks], sfr[m], 0, 0, 0);
      }
    }

    if (kt == 9){  // keys 576..639: only 576 valid
      #pragma unroll
      for (int m=0;m<4;m++)
        #pragma unroll
        for (int gg=0; gg<4; ++gg){
          int kb = 576 + m*16 + kg*4 + gg;
          if (kb >= SEQ) sfr[m][gg] = -1e30f;
        }
    }

    // online softmax (per lane = per q-column; reduce across kg groups)
    float tmax = -1e30f;
    #pragma unroll
    for (int m=0;m<4;m++)
      #pragma unroll
      for (int gg=0; gg<4; ++gg) tmax = fmaxf(tmax, sfr[m][gg]);
    tmax = fmaxf(tmax, __shfl_xor(tmax, 16));
    tmax = fmaxf(tmax, __shfl_xor(tmax, 32));
    float mn  = fmaxf(m_run, tmax);
    float scl = exp2f(m_run - mn);
    float ps  = 0.f;
    #pragma unroll
    for (int m=0;m<4;m++)
      #pragma unroll
      for (int gg=0; gg<4; ++gg){
        float pv = exp2f(sfr[m][gg] - mn);
        sfr[m][gg] = pv; ps += pv;
      }
    ps += __shfl_xor(ps, 16);
    ps += __shfl_xor(ps, 32);
    l_run = l_run*scl + ps;
    m_run = mn;
    #pragma unroll
    for (int mf=0; mf<4; ++mf) o[mf] *= scl;

    // P^T -> per-wave LDS ([q=16][key=64], 72-col pad), then B-frag reads
    bf16* Pw = &sP[wave][0];
    #pragma unroll
    for (int m=0;m<4;m++){
      short4 w;
      w.x = f2s(sfr[m][0]); w.y = f2s(sfr[m][1]);
      w.z = f2s(sfr[m][2]); w.w = f2s(sfr[m][3]);
      *(short4*)(Pw + r16*72 + m*16 + kg*4) = w;
    }
    asm volatile("s_waitcnt lgkmcnt(0)" ::: "memory");
    v8s pb0 = *(const v8s*)(Pw + r16*72 + kg*8);
    v8s pb1 = *(const v8s*)(Pw + r16*72 + 32 + kg*8);
    #pragma unroll
    for (int mf=0; mf<4; ++mf){
      int d = mf*16 + r16;
      v8s v0 = *(const v8s*)(Vt + d*64 + ((kg     ^ (d&7))*8));
      v8s v1 = *(const v8s*)(Vt + d*64 + (((4+kg) ^ (d&7))*8));
      o[mf] = __builtin_amdgcn_mfma_f32_16x16x32_bf16(v0, pb0, o[mf], 0, 0, 0);
      o[mf] = __builtin_amdgcn_mfma_f32_16x16x32_bf16(v1, pb1, o[mf], 0, 0, 0);
    }
  }

  // write y[token][h*64 + d], o layout: q = r16, d = mf*16 + kg*4 + gg
  const int qg = qt*64 + wave*16 + r16;
  if (qg < SEQ){
    float inv = 1.f / l_run;
    #pragma unroll
    for (int mf=0; mf<4; ++mf){
      short4 w;
      w.x = f2s(o[mf][0]*inv); w.y = f2s(o[mf][1]*inv);
      w.z = f2s(o[mf][2]*inv); w.w = f2s(o[mf][3]*inv);
      *(short4*)(y + (size_t)(b_*SEQ + qg)*C_DIM + h_*DHEAD + mf*16 + kg*4) = w;
    }
  }
}

// ---------------- MFMA GEMM: C[M,N] = A[M,K] * BT[N,K]^T ----------------
// 128x128 tile, BK=64, 4 waves (2x2), each wave 4x4 16x16x32 fragments.
// EPI 0: qk    -> bf16, +bias, *QSCALE for cols<768
// EPI 1: fc1   -> bf16, +bias, exact GELU
// EPI 2: resid -> fp32, +bias +resid[idx], guarded row<MREAL
// EPI 5: vT    -> bf16 into VtAll[b*768+row][key], +bias[row]
template<int EPI>
__global__ __launch_bounds__(256, 4) void gemm_bt(
    const bf16* __restrict__ A, int lda,
    const bf16* __restrict__ BT, int ldb,
    void* Cv, int ldc,
    const float* __restrict__ bias,
    const float* resid,
    int K)
{
  __shared__ alignas(16) bf16 sA[128*64];
  __shared__ alignas(16) bf16 sB[128*64];
  const int tid  = threadIdx.x;
  const int wave = tid>>6, lane = tid&63;
  const int wr = wave>>1, wc = wave&1;
  const int r16 = lane&15, kg = lane>>4;

  // XCD-bijective swizzle (m204)
  int nx = gridDim.x, nwg = nx*gridDim.y;
  int id = blockIdx.y*nx + blockIdx.x;
  int qq = nwg>>3, r8 = nwg&7, xcd = id&7, j = id>>3;
  int swz = (xcd<r8 ? xcd*(qq+1) : r8*(qq+1) + (xcd-r8)*qq) + j;
  int mt = swz / nx, nt = swz % nx;

  v4f acc[4][4];
  v4f zero4 = {0.f,0.f,0.f,0.f};
  #pragma unroll
  for (int m=0;m<4;m++)
    #pragma unroll
    for (int n=0;n<4;n++) acc[m][n] = zero4;

  const int mrow0 = mt*128, ncol0 = nt*128;

  for (int kt=0; kt<K; kt+=64){
    #pragma unroll
    for (int i=0;i<4;i++){
      int ci = wave*4 + i;
      int q  = ci*64 + lane;
      int rr = q>>3;
      int cc = (q&7)*8;
      const bf16* ga = A  + (size_t)(mrow0+rr)*lda + (kt+cc);
      const bf16* gb = BT + (size_t)(ncol0+rr)*ldb + (kt+cc);
      __builtin_amdgcn_global_load_lds(
          (const __attribute__((address_space(1))) void*)ga,
          (__attribute__((address_space(3))) void*)((char*)sA + ci*1024), 16, 0, 0);
      __builtin_amdgcn_global_load_lds(
          (const __attribute__((address_space(1))) void*)gb,
          (__attribute__((address_space(3))) void*)((char*)sB + ci*1024), 16, 0, 0);
    }
    __syncthreads();
    #pragma unroll
    for (int ks=0; ks<2; ks++){
      v8s av[4], bv[4];
      #pragma unroll
      for (int m=0;m<4;m++)
        av[m] = *(const v8s*)(sA + (wr*64 + m*16 + r16)*64 + ks*32 + kg*8);
      #pragma unroll
      for (int n=0;n<4;n++)
        bv[n] = *(const v8s*)(sB + (wc*64 + n*16 + r16)*64 + ks*32 + kg*8);
      #pragma unroll
      for (int m=0;m<4;m++)
        #pragma unroll
        for (int n=0;n<4;n++)
          acc[m][n] = __builtin_amdgcn_mfma_f32_16x16x32_bf16(av[m], bv[n], acc[m][n], 0, 0, 0);
    }
    __syncthreads();
  }

  // epilogue — C/D layout: col = lane&15, row = (lane>>4)*4 + reg
  #pragma unroll
  for (int m=0;m<4;m++){
    #pragma unroll
    for (int n=0;n<4;n++){
      int col = ncol0 + wc*64 + n*16 + r16;
      #pragma unroll
      for (int gg=0; gg<4; gg++){
        int row = mrow0 + wr*64 + m*16 + kg*4 + gg;
        float v = acc[m][n][gg];
        if constexpr (EPI==0){
          float oo = v + bias[col];
          if (col < C_DIM) oo *= QSCALE;
          ((bf16*)Cv)[(size_t)row*ldc + col] = f2b(oo);
        } else if constexpr (EPI==1){
          float xg = v + bias[col];
          float oo = 0.5f*xg*(1.f + erff(xg*0.70710678118654752f));
          ((bf16*)Cv)[(size_t)row*ldc + col] = f2b(oo);
        } else if constexpr (EPI==2){
          if (row < MREAL){
            size_t idx = (size_t)row*ldc + col;
            ((float*)Cv)[idx] = v + bias[col] + resid[idx];
          }
        } else { // EPI==5: row = v-outdim (h*64+d), col = global token g
          int g = col;
          if (g < MREAL){
            int b = g / SEQ;
            int key = g - b*SEQ;
            ((bf16*)Cv)[((size_t)b*C_DIM + row)*NKV + key] = f2b(v + bias[row]);
          }
        }
      }
    }
  }
}

// ---------------- launch ----------------

extern "C" void kernel_launch(void* const* d_in, const int* in_sizes, int n_in,
                              void* d_out, int out_size, void* d_ws, size_t ws_size,
                              hipStream_t stream)
{
  const float* x     = (const float*)d_in[0];
  const float* ln1g  = (const float*)d_in[1];
  const float* ln1b  = (const float*)d_in[2];
  const float* qkvw  = (const float*)d_in[3];
  const float* qkvb  = (const float*)d_in[4];
  const float* projw = (const float*)d_in[5];
  const float* projb = (const float*)d_in[6];
  const float* ln2g  = (const float*)d_in[7];
  const float* ln2b  = (const float*)d_in[8];
  const float* fc1w  = (const float*)d_in[9];
  const float* fc1b  = (const float*)d_in[10];
  const float* fc2w  = (const float*)d_in[11];
  const float* fc2b  = (const float*)d_in[12];
  float* out = (float*)d_out;

  char* p = (char*)d_ws;
  auto take = [&](size_t n){ char* r = p; p += (n + 255) & ~(size_t)255; return r; };
  bf16* qkvT = (bf16*)take((size_t)(3*C_DIM)*C_DIM*2);  // [2304][768] (q,k,v rows)
  bf16* projT= (bf16*)take((size_t)C_DIM*C_DIM*2);
  bf16* fc1T = (bf16*)take((size_t)HID*C_DIM*2);
  bf16* fc2T = (bf16*)take((size_t)C_DIM*HID*2);
  bf16* xn   = (bf16*)take((size_t)MPAD*C_DIM*2);
  bf16* xn2  = (bf16*)take((size_t)MPAD*C_DIM*2);
  bf16* qk   = (bf16*)take((size_t)MPAD*QKW*2);          // q,k only
  bf16* y    = (bf16*)take((size_t)MPAD*C_DIM*2);
  bf16* h    = (bf16*)take((size_t)MPAD*HID*2);
  bf16* VtAll= (bf16*)take((size_t)(BATCH*C_DIM + 2*DHEAD)*NKV*2); // [b*768+vo][key]

  // weight transposes (bf16 cast)
  k_transpose_cast<<<dim3(C_DIM/64, 3*C_DIM/64), 256, 0, stream>>>(qkvw, qkvT, C_DIM, 3*C_DIM);
  k_transpose_cast<<<dim3(C_DIM/64, C_DIM/64),  256, 0, stream>>>(projw, projT, C_DIM, C_DIM);
  k_transpose_cast<<<dim3(C_DIM/64, HID/64),    256, 0, stream>>>(fc1w, fc1T, C_DIM, HID);
  k_transpose_cast<<<dim3(HID/64,  C_DIM/64),   256, 0, stream>>>(fc2w, fc2T, HID, C_DIM);
  k_zero_pad<<<336, 256, 0, stream>>>(y);

  // LN1 -> xn
  k_layernorm<<<MPAD, 256, 0, stream>>>(x, ln1g, ln1b, xn);

  // qk = xn @ [Wq|Wk]^T + b  (q scaled by QSCALE)
  gemm_bt<0><<<dim3(QKW/128, MPAD/128), 256, 0, stream>>>(
      xn, C_DIM, qkvT, C_DIM, qk, QKW, qkvb, nullptr, C_DIM);

  // VtAll = (xn @ Wv)^T + bv, written as [b*768+vo][key]
  gemm_bt<5><<<dim3(MPAD/128, C_DIM/128), 256, 0, stream>>>(
      qkvT + (size_t)QKW*C_DIM, C_DIM, xn, C_DIM, VtAll, 0,
      qkvb + 2*C_DIM, nullptr, C_DIM);

  // fused flash attention -> y
  k_flash<<<1920, 256, 0, stream>>>(qk, VtAll, y);

  // x1 = x + y @ proj_w + b   -> d_out (fp32)
  gemm_bt<2><<<dim3(C_DIM/128, MPAD/128), 256, 0, stream>>>(
      y, C_DIM, projT, C_DIM, out, C_DIM, projb, x, C_DIM);

  // LN2 -> xn2
  k_layernorm<<<MPAD, 256, 0, stream>>>(out, ln2g, ln2b, xn2);

  // h = gelu(xn2 @ fc1_w + b)
  gemm_bt<1><<<dim3(HID/128, MPAD/128), 256, 0, stream>>>(
      xn2, C_DIM, fc1T, C_DIM, h, HID, fc1b, nullptr, C_DIM);

  // out = x1 + h @ fc2_w + b
  gemm_bt<2><<<dim3(C_DIM/128, MPAD/128), 256, 0, stream>>>(
      h, HID, fc2T, HID, out, C_DIM, fc2b, out, HID);
}